// Round 1
// baseline (1069.605 us; speedup 1.0000x reference)
//
#include <hip/hip_runtime.h>
#include <math.h>

#define H 2048
#define NH 16
#define NKV 4
#define HD 128
#define BB 2
#define SS 2048
#define NT (BB*SS)           // 4096 tokens
#define NQK (NH*HD)          // 2048
#define NKVD (NKV*HD)        // 512
#define NQKV (NQK + 2*NKVD)  // 3072
#define EPSV 1e-6f
#define SM_SCALE 0.08838834764831845f

using s8v = __attribute__((ext_vector_type(8))) short;
using s4v = __attribute__((ext_vector_type(4))) short;
using f4v = __attribute__((ext_vector_type(4))) float;

__device__ inline float bf2f(short s){ unsigned u = ((unsigned)(unsigned short)s) << 16; return __builtin_bit_cast(float, u); }
__device__ inline short f2bf(float f){ unsigned u = __builtin_bit_cast(unsigned, f); u += 0x7FFF + ((u>>16)&1); return (short)(u>>16); }

__device__ inline f4v mfma16(s8v a, s8v b, f4v c){
    return __builtin_amdgcn_mfma_f32_16x16x32_bf16(a, b, c, 0, 0, 0);
}

// ---------------- conversion kernels ----------------

__global__ void cvt_f32_bf16(const float* __restrict__ in, short* __restrict__ out, int n4){
    int i = blockIdx.x*blockDim.x + threadIdx.x;
    int stride = gridDim.x*blockDim.x;
    for (; i < n4; i += stride){
        float4 v = reinterpret_cast<const float4*>(in)[i];
        s4v o = { f2bf(v.x), f2bf(v.y), f2bf(v.z), f2bf(v.w) };
        reinterpret_cast<s4v*>(out)[i] = o;
    }
}

__global__ void concat_w(const float* __restrict__ Wq, const float* __restrict__ Wk,
                         const float* __restrict__ Wv, short* __restrict__ Wc, int n4total){
    int i = blockIdx.x*blockDim.x + threadIdx.x;
    int stride = gridDim.x*blockDim.x;
    for (; i < n4total; i += stride){
        int k  = i / (NQKV/4);
        int n  = (i % (NQKV/4)) * 4;
        const float* src;
        if (n < NQK)            src = Wq + (size_t)k*NQK  + n;
        else if (n < NQK+NKVD)  src = Wk + (size_t)k*NKVD + (n - NQK);
        else                    src = Wv + (size_t)k*NKVD + (n - NQK - NKVD);
        float4 v = *reinterpret_cast<const float4*>(src);
        s4v o = { f2bf(v.x), f2bf(v.y), f2bf(v.z), f2bf(v.w) };
        *reinterpret_cast<s4v*>(Wc + (size_t)k*NQKV + n) = o;
    }
}

__global__ void concat_b(const float* __restrict__ bq, const float* __restrict__ bk,
                         const float* __restrict__ bv, float* __restrict__ Bc){
    int i = blockIdx.x*blockDim.x + threadIdx.x;
    if (i < NQKV)
        Bc[i] = (i < NQK) ? bq[i] : (i < NQK+NKVD ? bk[i-NQK] : bv[i-NQK-NKVD]);
}

// ---------------- generic bf16 MFMA GEMM: C = A @ B + bias ----------------
// A: M x K row-major bf16, B: K x N row-major bf16, bias fp32[N]
// OUT_F32: 1 -> float out, 0 -> bf16 out

template<int OUT_F32>
__global__ __launch_bounds__(256) void gemm_bf16(const short* __restrict__ A, const short* __restrict__ Bw,
                                                 const float* __restrict__ bias, void* __restrict__ Cout,
                                                 int M, int N, int K){
    __shared__ short As[128][48];
    __shared__ short Bt[128][48];
    const int tid  = threadIdx.x;
    const int lane = tid & 63;
    const int w    = tid >> 6;
    const int m0   = blockIdx.y * 128;
    const int n0   = blockIdx.x * 128;
    const int mb   = (w & 1) * 64;
    const int nb   = (w >> 1) * 64;
    f4v acc[4][4] = {};

    for (int k0 = 0; k0 < K; k0 += 32){
        // stage A: 128 rows x 32 cols
        #pragma unroll
        for (int c = 0; c < 2; ++c){
            int ch = tid + c*256;
            int row = ch >> 2, col = (ch & 3) * 8;
            s8v v = *reinterpret_cast<const s8v*>(A + (size_t)(m0+row)*K + k0 + col);
            *reinterpret_cast<s8v*>(&As[row][col]) = v;
        }
        // stage B transposed: source 32 rows(k) x 128 cols(n) -> Bt[n][k]
        #pragma unroll
        for (int c = 0; c < 2; ++c){
            int ch = tid + c*256;
            int row = ch >> 4, col = (ch & 15) * 8;
            s8v v = *reinterpret_cast<const s8v*>(Bw + (size_t)(k0+row)*N + n0 + col);
            #pragma unroll
            for (int j = 0; j < 8; ++j) Bt[col + j][row] = v[j];
        }
        __syncthreads();
        s8v a[4], b[4];
        #pragma unroll
        for (int i = 0; i < 4; ++i) a[i] = *reinterpret_cast<const s8v*>(&As[mb + i*16 + (lane&15)][(lane>>4)*8]);
        #pragma unroll
        for (int j = 0; j < 4; ++j) b[j] = *reinterpret_cast<const s8v*>(&Bt[nb + j*16 + (lane&15)][(lane>>4)*8]);
        #pragma unroll
        for (int i = 0; i < 4; ++i)
            #pragma unroll
            for (int j = 0; j < 4; ++j)
                acc[i][j] = mfma16(a[i], b[j], acc[i][j]);
        __syncthreads();
    }

    #pragma unroll
    for (int i = 0; i < 4; ++i){
        #pragma unroll
        for (int j = 0; j < 4; ++j){
            int col = n0 + nb + j*16 + (lane & 15);
            float bvv = bias ? bias[col] : 0.f;
            #pragma unroll
            for (int r = 0; r < 4; ++r){
                int row = m0 + mb + i*16 + (lane>>4)*4 + r;
                float vv = acc[i][j][r] + bvv;
                if (OUT_F32) reinterpret_cast<float*>(Cout)[(size_t)row*N + col] = vv;
                else         reinterpret_cast<short*>(Cout)[(size_t)row*N + col] = f2bf(vv);
            }
        }
    }
}

// ---------------- fused RMSNorm + RoPE on q,k (in place in QKV, bf16) ----------------
// one wave per (token, head) row of 128; lane handles dims [lane] and [lane+64]

__global__ __launch_bounds__(256) void norm_rope(short* __restrict__ qkv, const float* __restrict__ cosb,
                                                 const float* __restrict__ sinb, const float* __restrict__ qw,
                                                 const float* __restrict__ kw){
    int row  = blockIdx.x * 4 + (threadIdx.x >> 6);
    int lane = threadIdx.x & 63;
    const int QROWS = NT * NH;
    short* ptr; const float* w; float outscale; int token;
    if (row < QROWS){
        token = row >> 4; int h = row & 15;
        ptr = qkv + (size_t)token*NQKV + h*HD; w = qw; outscale = SM_SCALE;
    } else {
        int rr = row - QROWS;
        token = rr >> 2; int h = rr & 3;
        ptr = qkv + (size_t)token*NQKV + NQK + h*HD; w = kw; outscale = 1.f;
    }
    int s = token & (SS-1);
    float x1 = bf2f(ptr[lane]), x2 = bf2f(ptr[lane+64]);
    float ssq = x1*x1 + x2*x2;
    #pragma unroll
    for (int off = 32; off; off >>= 1) ssq += __shfl_xor(ssq, off, 64);
    float inv = rsqrtf(ssq * (1.f/128.f) + EPSV);
    float n1 = x1 * inv * w[lane];
    float n2 = x2 * inv * w[lane+64];
    float c1 = cosb[s*HD + lane], c2 = cosb[s*HD + lane + 64];
    float s1 = sinb[s*HD + lane], s2 = sinb[s*HD + lane + 64];
    float o1 = (n1*c1 - n2*s1) * outscale;
    float o2 = (n2*c2 + n1*s2) * outscale;
    ptr[lane]    = f2bf(o1);
    ptr[lane+64] = f2bf(o2);
}

// ---------------- V transpose: qkv v-part -> Vt[b*NKVD + (kv*128+d)][s] ----------------

__global__ void vtrans(const short* __restrict__ qkv, short* __restrict__ Vt){
    int i = blockIdx.x*blockDim.x + threadIdx.x;
    int strd = gridDim.x*blockDim.x;
    const int total = NT * NKVD;
    for (; i < total; i += strd){
        int token = i >> 9;         // / 512
        int c     = i & 511;        // kv*128 + d
        short v = qkv[(size_t)token*NQKV + NQK + NKVD + c];
        int b = token >> 11;        // / 2048
        int sidx = token & (SS-1);
        Vt[((size_t)(b*NKVD + c))*SS + sidx] = v;
    }
}

// ---------------- flash attention (causal, GQA 4:1) ----------------
// grid: (S/64, NH, B), 256 threads = 4 waves; wave handles 16 q rows.

__global__ __launch_bounds__(256) void attn_fwd(const short* __restrict__ qkv, const short* __restrict__ Vt,
                                                short* __restrict__ attn){
    const int lane = threadIdx.x & 63;
    const int w    = threadIdx.x >> 6;
    const int qb   = blockIdx.x;
    const int h    = blockIdx.y;
    const int b    = blockIdx.z;
    const int kvh  = h >> 2;
    const int q0   = qb*64 + w*16;
    __shared__ short Pl[4][16][32];
    short (*P)[32] = Pl[w];

    // Q fragments (scale already folded in by norm_rope)
    s8v qa[4];
    const short* qbase = qkv + (size_t)(b*SS + q0 + (lane&15))*NQKV + h*HD + (lane>>4)*8;
    #pragma unroll
    for (int dc = 0; dc < 4; ++dc) qa[dc] = *reinterpret_cast<const s8v*>(qbase + dc*32);

    f4v acc_o[8] = {};
    float mrow[4], lrow[4];
    #pragma unroll
    for (int r = 0; r < 4; ++r){ mrow[r] = -3e38f; lrow[r] = 0.f; }

    const int kv_end = q0 + 16;
    for (int kv0 = 0; kv0 < kv_end; kv0 += 32){
        // S = Q @ K^T  (two 16-key halves)
        f4v sfr[2] = {};
        #pragma unroll
        for (int kh = 0; kh < 2; ++kh){
            int key  = kv0 + kh*16 + (lane & 15);
            int keyc = key < SS ? key : SS-1;
            const short* kb = qkv + (size_t)(b*SS + keyc)*NQKV + NQK + kvh*HD + (lane>>4)*8;
            #pragma unroll
            for (int dc = 0; dc < 4; ++dc)
                sfr[kh] = mfma16(qa[dc], *reinterpret_cast<const s8v*>(kb + dc*32), sfr[kh]);
        }
        const bool needmask = (kv0 + 31) > q0;
        int key0 = kv0 + (lane & 15);
        // online softmax per D-row
        #pragma unroll
        for (int r = 0; r < 4; ++r){
            int qrow = q0 + (lane>>4)*4 + r;
            float s0 = sfr[0][r], s1 = sfr[1][r];
            if (needmask){
                if (key0      > qrow) s0 = -3e38f;
                if (key0 + 16 > qrow) s1 = -3e38f;
            }
            float mx = fmaxf(s0, s1);
            #pragma unroll
            for (int off = 8; off; off >>= 1) mx = fmaxf(mx, __shfl_xor(mx, off, 16));
            float mnew  = fmaxf(mrow[r], mx);
            float alpha = __expf(mrow[r] - mnew);
            float p0 = __expf(s0 - mnew);
            float p1 = __expf(s1 - mnew);
            short p0b = f2bf(p0), p1b = f2bf(p1);
            float psum = bf2f(p0b) + bf2f(p1b);
            #pragma unroll
            for (int off = 8; off; off >>= 1) psum += __shfl_xor(psum, off, 16);
            lrow[r] = lrow[r]*alpha + psum;
            mrow[r] = mnew;
            #pragma unroll
            for (int df = 0; df < 8; ++df) acc_o[df][r] *= alpha;
            P[(lane>>4)*4 + r][(lane & 15)]      = p0b;
            P[(lane>>4)*4 + r][16 + (lane & 15)] = p1b;
        }
        // P @ V via transposed V
        s8v pa = *reinterpret_cast<const s8v*>(&P[lane & 15][(lane>>4)*8]);
        const short* vb = Vt + ((size_t)(b*NKVD + kvh*HD + (lane & 15)))*SS + kv0 + (lane>>4)*8;
        #pragma unroll
        for (int df = 0; df < 8; ++df)
            acc_o[df] = mfma16(pa, *reinterpret_cast<const s8v*>(vb + (size_t)df*16*SS), acc_o[df]);
    }

    // epilogue
    #pragma unroll
    for (int r = 0; r < 4; ++r){
        int qrow = q0 + (lane>>4)*4 + r;
        float invl = 1.f / lrow[r];
        short* ob = attn + (size_t)(b*SS + qrow)*NQK + h*HD;
        #pragma unroll
        for (int df = 0; df < 8; ++df)
            ob[df*16 + (lane & 15)] = f2bf(acc_o[df][r] * invl);
    }
}

// ---------------- launch ----------------

extern "C" void kernel_launch(void* const* d_in, const int* in_sizes, int n_in,
                              void* d_out, int out_size, void* d_ws, size_t ws_size,
                              hipStream_t stream){
    (void)in_sizes; (void)n_in; (void)out_size; (void)ws_size;
    const float* hs   = (const float*)d_in[0];
    const float* cosb = (const float*)d_in[1];
    const float* sinb = (const float*)d_in[2];
    const float* Wq   = (const float*)d_in[3];
    const float* bq   = (const float*)d_in[4];
    const float* Wk   = (const float*)d_in[5];
    const float* bk   = (const float*)d_in[6];
    const float* Wv   = (const float*)d_in[7];
    const float* bv   = (const float*)d_in[8];
    const float* Wo   = (const float*)d_in[9];
    const float* bo   = (const float*)d_in[10];
    const float* qw   = (const float*)d_in[11];
    const float* kw   = (const float*)d_in[12];
    float* out = (float*)d_out;
    char* ws = (char*)d_ws;

    size_t off = 0;
    auto alloc = [&](size_t bytes){ size_t o = off; off += (bytes + 255) & ~(size_t)255; return o; };
    short* Xb    = (short*)(ws + alloc((size_t)NT*H*2));
    short* Wc    = (short*)(ws + alloc((size_t)H*NQKV*2));
    float* Bc    = (float*)(ws + alloc((size_t)NQKV*4));
    short* QKV   = (short*)(ws + alloc((size_t)NT*NQKV*2));
    short* Vt    = (short*)(ws + alloc((size_t)BB*NKVD*SS*2 + 4096));
    short* attnb = (short*)(ws + alloc((size_t)NT*NQK*2));
    short* WoB   = (short*)(ws + alloc((size_t)NQK*H*2));

    cvt_f32_bf16<<<2048, 256, 0, stream>>>(hs, Xb, NT*H/4);
    cvt_f32_bf16<<<1024, 256, 0, stream>>>(Wo, WoB, NQK*H/4);
    concat_w<<<2048, 256, 0, stream>>>(Wq, Wk, Wv, Wc, H*(NQKV/4));
    concat_b<<<3, 1024, 0, stream>>>(bq, bk, bv, Bc);

    gemm_bf16<0><<<dim3(NQKV/128, NT/128), 256, 0, stream>>>(Xb, Wc, Bc, QKV, NT, NQKV, H);
    norm_rope<<<(NT*(NH+NKV))/4, 256, 0, stream>>>(QKV, cosb, sinb, qw, kw);
    vtrans<<<2048, 256, 0, stream>>>(QKV, Vt);
    attn_fwd<<<dim3(SS/64, NH, BB), 256, 0, stream>>>(QKV, Vt, attnb);
    gemm_bf16<1><<<dim3(H/128, NT/128), 256, 0, stream>>>(attnb, WoB, bo, out, NT, H, NQK);
}

// Round 2
// 607.838 us; speedup vs baseline: 1.7597x; 1.7597x over previous
//
#include <hip/hip_runtime.h>
#include <math.h>

#define H 2048
#define NH 16
#define NKV 4
#define HD 128
#define BB 2
#define SS 2048
#define NT (BB*SS)           // 4096 tokens
#define NQK (NH*HD)          // 2048
#define NKVD (NKV*HD)        // 512
#define NQKV (NQK + 2*NKVD)  // 3072
#define EPSV 1e-6f
#define SM_SCALE 0.08838834764831845f

using s8v = __attribute__((ext_vector_type(8))) short;
using s4v = __attribute__((ext_vector_type(4))) short;
using f4v = __attribute__((ext_vector_type(4))) float;

typedef unsigned int __attribute__((address_space(1))) u32_g;
typedef unsigned int __attribute__((address_space(3))) u32_l;

__device__ inline float bf2f(short s){ unsigned u = ((unsigned)(unsigned short)s) << 16; return __builtin_bit_cast(float, u); }
__device__ inline short f2bf(float f){ unsigned u = __builtin_bit_cast(unsigned, f); u += 0x7FFF + ((u>>16)&1); return (short)(u>>16); }

__device__ inline f4v mfma16(s8v a, s8v b, f4v c){
    return __builtin_amdgcn_mfma_f32_16x16x32_bf16(a, b, c, 0, 0, 0);
}

__device__ inline void gl_lds16(const short* g, short* l){
    __builtin_amdgcn_global_load_lds((const u32_g*)g, (u32_l*)l, 16, 0, 0);
}

// ---------------- conversion / prep kernels ----------------

__global__ void cvt_f32_bf16(const float* __restrict__ in, short* __restrict__ out, int n4){
    int i = blockIdx.x*blockDim.x + threadIdx.x;
    int stride = gridDim.x*blockDim.x;
    for (; i < n4; i += stride){
        float4 v = reinterpret_cast<const float4*>(in)[i];
        s4v o = { f2bf(v.x), f2bf(v.y), f2bf(v.z), f2bf(v.w) };
        reinterpret_cast<s4v*>(out)[i] = o;
    }
}

// fp32 src [R][C] -> bf16 dst [C][R]; R, C multiples of 64
__global__ __launch_bounds__(256) void transpose_cvt(const float* __restrict__ src, short* __restrict__ dst,
                                                     int R, int C){
    __shared__ short t[64][72];
    const int tid = threadIdx.x;
    const int r0 = blockIdx.y*64, c0 = blockIdx.x*64;
    #pragma unroll
    for (int it = 0; it < 4; ++it){
        int ch = tid + it*256;
        int row = ch >> 4, c4 = (ch & 15) * 4;
        float4 v = *reinterpret_cast<const float4*>(src + (size_t)(r0+row)*C + c0 + c4);
        t[row][c4+0] = f2bf(v.x); t[row][c4+1] = f2bf(v.y);
        t[row][c4+2] = f2bf(v.z); t[row][c4+3] = f2bf(v.w);
    }
    __syncthreads();
    #pragma unroll
    for (int it = 0; it < 4; ++it){
        int ch = tid + it*256;
        int cc = ch >> 4, r4 = (ch & 15) * 4;
        s4v o = { t[r4+0][cc], t[r4+1][cc], t[r4+2][cc], t[r4+3][cc] };
        *reinterpret_cast<s4v*>(dst + (size_t)(c0+cc)*R + r0 + r4) = o;
    }
}

__global__ void concat_b(const float* __restrict__ bq, const float* __restrict__ bk,
                         const float* __restrict__ bv, float* __restrict__ Bc){
    int i = blockIdx.x*blockDim.x + threadIdx.x;
    if (i < NQKV)
        Bc[i] = (i < NQK) ? bq[i] : (i < NQK+NKVD ? bk[i-NQK] : bv[i-NQK-NKVD]);
}

// ---------------- m97-style GEMM: C = A @ BT^T + bias ----------------
// A: M x K row-major bf16; BT: N x K row-major bf16 (i.e. B transposed)

template<int OUT_F32>
__global__ __launch_bounds__(256) void gemm_bt(const short* __restrict__ A, const short* __restrict__ BT,
                                               const float* __restrict__ bias, void* __restrict__ Cout,
                                               int M, int N, int K){
    __shared__ short As[2][4096];   // 128 rows x 32 k
    __shared__ short Bs[2][4096];
    const int tid  = threadIdx.x;
    const int lane = tid & 63;
    const int wv   = tid >> 6;
    const int f    = lane & 15;
    const int g    = lane >> 4;
    const int m0   = blockIdx.y * 128;
    const int n0   = blockIdx.x * 128;
    const int mb   = (wv & 1) * 64;
    const int nb   = (wv >> 1) * 64;
    f4v acc[4][4] = {};

    const short* Abase = A  + (size_t)m0*K;
    const short* Bbase = BT + (size_t)n0*K;
    const int srow = (lane >> 2);
    const int scol = (lane & 3) * 8;

    auto STAGE = [&](int buf, int k0){
        #pragma unroll
        for (int c = 0; c < 2; ++c){
            int issue = wv + c*4;
            int row = issue*16 + srow;
            gl_lds16(Abase + (size_t)row*K + k0 + scol, &As[buf][issue*512]);
            gl_lds16(Bbase + (size_t)row*K + k0 + scol, &Bs[buf][issue*512]);
        }
    };

    STAGE(0, 0);
    asm volatile("s_waitcnt vmcnt(0)" ::: "memory");
    __syncthreads();
    int cur = 0;
    for (int k0 = 0; k0 < K; k0 += 32){
        if (k0 + 32 < K) STAGE(cur^1, k0 + 32);
        s8v a[4], bfr[4];
        #pragma unroll
        for (int i = 0; i < 4; ++i) a[i]   = *reinterpret_cast<const s8v*>(&As[cur][(mb + i*16 + f)*32 + g*8]);
        #pragma unroll
        for (int j = 0; j < 4; ++j) bfr[j] = *reinterpret_cast<const s8v*>(&Bs[cur][(nb + j*16 + f)*32 + g*8]);
        #pragma unroll
        for (int i = 0; i < 4; ++i)
            #pragma unroll
            for (int j = 0; j < 4; ++j)
                acc[i][j] = mfma16(a[i], bfr[j], acc[i][j]);
        asm volatile("s_waitcnt vmcnt(0)" ::: "memory");
        __syncthreads();
        cur ^= 1;
    }

    #pragma unroll
    for (int i = 0; i < 4; ++i){
        #pragma unroll
        for (int j = 0; j < 4; ++j){
            int col = n0 + nb + j*16 + f;
            float bvv = bias ? bias[col] : 0.f;
            #pragma unroll
            for (int r = 0; r < 4; ++r){
                int row = m0 + mb + i*16 + g*4 + r;
                float vv = acc[i][j][r] + bvv;
                if (OUT_F32) reinterpret_cast<float*>(Cout)[(size_t)row*N + col] = vv;
                else         reinterpret_cast<short*>(Cout)[(size_t)row*N + col] = f2bf(vv);
            }
        }
    }
}

// ---------------- fused RMSNorm + RoPE on q,k (in place, bf16) ----------------

__global__ __launch_bounds__(256) void norm_rope(short* __restrict__ qkv, const float* __restrict__ cosb,
                                                 const float* __restrict__ sinb, const float* __restrict__ qw,
                                                 const float* __restrict__ kw){
    int row  = blockIdx.x * 4 + (threadIdx.x >> 6);
    int lane = threadIdx.x & 63;
    const int QROWS = NT * NH;
    short* ptr; const float* w; float outscale; int token;
    if (row < QROWS){
        token = row >> 4; int h = row & 15;
        ptr = qkv + (size_t)token*NQKV + h*HD; w = qw; outscale = SM_SCALE;
    } else {
        int rr = row - QROWS;
        token = rr >> 2; int h = rr & 3;
        ptr = qkv + (size_t)token*NQKV + NQK + h*HD; w = kw; outscale = 1.f;
    }
    int s = token & (SS-1);
    float x1 = bf2f(ptr[lane]), x2 = bf2f(ptr[lane+64]);
    float ssq = x1*x1 + x2*x2;
    #pragma unroll
    for (int off = 32; off; off >>= 1) ssq += __shfl_xor(ssq, off, 64);
    float inv = rsqrtf(ssq * (1.f/128.f) + EPSV);
    float n1 = x1 * inv * w[lane];
    float n2 = x2 * inv * w[lane+64];
    float c1 = cosb[s*HD + lane], c2 = cosb[s*HD + lane + 64];
    float s1 = sinb[s*HD + lane], s2 = sinb[s*HD + lane + 64];
    float o1 = (n1*c1 - n2*s1) * outscale;
    float o2 = (n2*c2 + n1*s2) * outscale;
    ptr[lane]    = f2bf(o1);
    ptr[lane+64] = f2bf(o2);
}

// ---------------- V transpose: qkv v-part -> Vt[b*NKVD + (kv*128+d)][s] ----------------

__global__ void vtrans(const short* __restrict__ qkv, short* __restrict__ Vt){
    int i = blockIdx.x*blockDim.x + threadIdx.x;
    int strd = gridDim.x*blockDim.x;
    const int total = NT * NKVD;
    for (; i < total; i += strd){
        int token = i >> 9;
        int c     = i & 511;
        short v = qkv[(size_t)token*NQKV + NQK + NKVD + c];
        int b = token >> 11;
        int sidx = token & (SS-1);
        Vt[((size_t)(b*NKVD + c))*SS + sidx] = v;
    }
}

// ---------------- flash attention (causal, GQA 4:1) ----------------
// grid (16, NH, B); 4 waves; block owns 128 q rows, wave owns 32 (row-interleaved).
// K staged in dbuf swizzled LDS via global_load_lds; V from global (L2-resident).

__global__ __launch_bounds__(256) void attn_fwd(const short* __restrict__ qkv, const short* __restrict__ Vt,
                                                short* __restrict__ attn){
    __shared__ short Ks[2][8192];   // 64 keys x 128 d, XOR-swizzled
    __shared__ short Ps[4][2048];   // per-wave P: 32 q x 64 k, XOR-swizzled
    const int tid  = threadIdx.x;
    const int lane = tid & 63;
    const int w    = tid >> 6;
    const int f    = lane & 15;
    const int g    = lane >> 4;
    const int qt   = (int)gridDim.x - 1 - (int)blockIdx.x;  // heavy tiles first
    const int h    = blockIdx.y;
    const int b    = blockIdx.z;
    const int kvh  = h >> 2;
    const int q0   = qt * 128;
    char* Pb = (char*)Ps[w];

    auto STAGEK = [&](int buf, int kv0){
        #pragma unroll
        for (int c = 0; c < 4; ++c){
            int issue = w + c*4;
            int row = issue*4 + g;          // g = lane>>4
            int col16 = f ^ (row & 7);      // pre-swizzled source (rule 21)
            gl_lds16(qkv + (size_t)(b*SS + kv0 + row)*NQKV + NQK + kvh*HD + col16*8,
                     &Ks[buf][issue*512]);
        }
    };

    // Q fragments; fragment row f -> qrow(i,f) = q0 + w*4 + (f&3) + (f>>2)*16 + i*64
    s8v qa[2][4];
    const int qrow_a = q0 + w*4 + (f & 3) + ((f >> 2) << 4);
    #pragma unroll
    for (int i = 0; i < 2; ++i)
        #pragma unroll
        for (int dc = 0; dc < 4; ++dc)
            qa[i][dc] = *reinterpret_cast<const s8v*>(
                qkv + (size_t)(b*SS + qrow_a + i*64)*NQKV + h*HD + dc*32 + g*8);

    f4v acc[2][8] = {};
    float m_[2][4], l_[2][4];
    #pragma unroll
    for (int i = 0; i < 2; ++i)
        #pragma unroll
        for (int r = 0; r < 4; ++r){ m_[i][r] = -3e38f; l_[i][r] = 0.f; }

    const int nt = qt*2 + 2;
    STAGEK(0, 0);
    asm volatile("s_waitcnt vmcnt(0)" ::: "memory");
    __syncthreads();
    int cur = 0;

    for (int t = 0; t < nt; ++t){
        const int kv0 = t*64;
        if (t + 1 < nt) STAGEK(cur^1, kv0 + 64);

        // ---- QK^T: sf[i][kh], C layout: col=f=key(16), row=g*4+r=qfrag ----
        f4v sf[2][4] = {};
        #pragma unroll
        for (int kh = 0; kh < 4; ++kh){
            s8v kb[4];
            const int krow = kh*16 + f;
            #pragma unroll
            for (int dc = 0; dc < 4; ++dc)
                kb[dc] = *reinterpret_cast<const s8v*>(
                    (const char*)Ks[cur] + krow*256 + ((dc*64 + g*16) ^ ((krow & 7) << 4)));
            #pragma unroll
            for (int i = 0; i < 2; ++i)
                #pragma unroll
                for (int dc = 0; dc < 4; ++dc)
                    sf[i][kh] = mfma16(qa[i][dc], kb[dc], sf[i][kh]);
        }

        // ---- causal mask ----
        if (kv0 + 63 > q0 + w*4){
            #pragma unroll
            for (int i = 0; i < 2; ++i)
                #pragma unroll
                for (int kh = 0; kh < 4; ++kh){
                    int key = kv0 + kh*16 + f;
                    #pragma unroll
                    for (int r = 0; r < 4; ++r){
                        int qrow = q0 + w*4 + r + g*16 + i*64;
                        if (key > qrow) sf[i][kh][r] = -3e38f;
                    }
                }
        }

        // ---- online softmax (defer-max, THR=8) ----
        float pm[2][4];
        bool need = false;
        #pragma unroll
        for (int i = 0; i < 2; ++i)
            #pragma unroll
            for (int r = 0; r < 4; ++r){
                float mx = fmaxf(fmaxf(sf[i][0][r], sf[i][1][r]), fmaxf(sf[i][2][r], sf[i][3][r]));
                #pragma unroll
                for (int off = 8; off; off >>= 1) mx = fmaxf(mx, __shfl_xor(mx, off, 16));
                pm[i][r] = mx;
                need = need || (mx > m_[i][r] + 8.f);
            }
        if (__any(need)){
            #pragma unroll
            for (int i = 0; i < 2; ++i)
                #pragma unroll
                for (int r = 0; r < 4; ++r){
                    float mn = fmaxf(m_[i][r], pm[i][r]);
                    float al = __expf(m_[i][r] - mn);
                    m_[i][r] = mn;
                    l_[i][r] *= al;
                    #pragma unroll
                    for (int df = 0; df < 8; ++df) acc[i][df][r] *= al;
                }
        }

        // ---- P = exp(S - m), write to swizzled per-wave LDS, accumulate l ----
        #pragma unroll
        for (int i = 0; i < 2; ++i)
            #pragma unroll
            for (int r = 0; r < 4; ++r){
                const int prow = i*16 + g*4 + r;
                float ps = 0.f;
                #pragma unroll
                for (int kh = 0; kh < 4; ++kh){
                    float p = __expf(sf[i][kh][r] - m_[i][r]);
                    short pb = f2bf(p);
                    ps += bf2f(pb);
                    *(short*)(Pb + prow*128 + ((unsigned)((kh*16 + f)*2) ^ ((prow & 7) << 4))) = pb;
                }
                #pragma unroll
                for (int off = 8; off; off >>= 1) ps += __shfl_xor(ps, off, 16);
                l_[i][r] += ps;
            }

        asm volatile("s_waitcnt lgkmcnt(0)" ::: "memory");
        __builtin_amdgcn_sched_barrier(0);

        // ---- PV: O += P @ V (V^T from global, L2-resident) ----
        #pragma unroll
        for (int ks = 0; ks < 2; ++ks){
            s8v pa[2];
            #pragma unroll
            for (int i = 0; i < 2; ++i){
                const int prow = i*16 + f;
                pa[i] = *reinterpret_cast<const s8v*>(
                    Pb + prow*128 + ((ks*64 + g*16) ^ ((prow & 7) << 4)));
            }
            const short* vbase = Vt + ((size_t)(b*NKVD + kvh*HD + f))*SS + kv0 + ks*32 + g*8;
            s8v vb[8];
            #pragma unroll
            for (int df = 0; df < 8; ++df)
                vb[df] = *reinterpret_cast<const s8v*>(vbase + (size_t)df*16*SS);
            #pragma unroll
            for (int i = 0; i < 2; ++i)
                #pragma unroll
                for (int df = 0; df < 8; ++df)
                    acc[i][df] = mfma16(pa[i], vb[df], acc[i][df]);
        }

        asm volatile("s_waitcnt vmcnt(0)" ::: "memory");
        __syncthreads();
        cur ^= 1;
    }

    // ---- epilogue ----
    #pragma unroll
    for (int i = 0; i < 2; ++i)
        #pragma unroll
        for (int r = 0; r < 4; ++r){
            int qrow = q0 + w*4 + r + g*16 + i*64;
            float inv = 1.f / l_[i][r];
            short* ob = attn + (size_t)(b*SS + qrow)*NQK + h*HD;
            #pragma unroll
            for (int df = 0; df < 8; ++df)
                ob[df*16 + f] = f2bf(acc[i][df][r] * inv);
        }
}

// ---------------- launch ----------------

extern "C" void kernel_launch(void* const* d_in, const int* in_sizes, int n_in,
                              void* d_out, int out_size, void* d_ws, size_t ws_size,
                              hipStream_t stream){
    (void)in_sizes; (void)n_in; (void)out_size; (void)ws_size;
    const float* hs   = (const float*)d_in[0];
    const float* cosb = (const float*)d_in[1];
    const float* sinb = (const float*)d_in[2];
    const float* Wq   = (const float*)d_in[3];
    const float* bq   = (const float*)d_in[4];
    const float* Wk   = (const float*)d_in[5];
    const float* bk   = (const float*)d_in[6];
    const float* Wv   = (const float*)d_in[7];
    const float* bv   = (const float*)d_in[8];
    const float* Wo   = (const float*)d_in[9];
    const float* bo   = (const float*)d_in[10];
    const float* qw   = (const float*)d_in[11];
    const float* kw   = (const float*)d_in[12];
    float* out = (float*)d_out;
    char* ws = (char*)d_ws;

    size_t off = 0;
    auto alloc = [&](size_t bytes){ size_t o = off; off += (bytes + 255) & ~(size_t)255; return o; };
    short* Xb    = (short*)(ws + alloc((size_t)NT*H*2));
    short* Wct   = (short*)(ws + alloc((size_t)NQKV*H*2));   // [3072][2048] = [q;k;v]^T
    float* Bc    = (float*)(ws + alloc((size_t)NQKV*4));
    short* QKV   = (short*)(ws + alloc((size_t)NT*NQKV*2));
    short* Vt    = (short*)(ws + alloc((size_t)BB*NKVD*SS*2 + 4096));
    short* attnb = (short*)(ws + alloc((size_t)NT*NQK*2));
    short* WoT   = (short*)(ws + alloc((size_t)H*NQK*2));    // [2048 n][2048 k]

    cvt_f32_bf16<<<2048, 256, 0, stream>>>(hs, Xb, NT*H/4);
    transpose_cvt<<<dim3(NQK/64,  H/64), 256, 0, stream>>>(Wq, Wct,                      H, NQK);
    transpose_cvt<<<dim3(NKVD/64, H/64), 256, 0, stream>>>(Wk, Wct + (size_t)NQK*H,      H, NKVD);
    transpose_cvt<<<dim3(NKVD/64, H/64), 256, 0, stream>>>(Wv, Wct + (size_t)(NQK+NKVD)*H, H, NKVD);
    transpose_cvt<<<dim3(H/64,  NQK/64), 256, 0, stream>>>(Wo, WoT,                      NQK, H);
    concat_b<<<3, 1024, 0, stream>>>(bq, bk, bv, Bc);

    gemm_bt<0><<<dim3(NQKV/128, NT/128), 256, 0, stream>>>(Xb, Wct, Bc, QKV, NT, NQKV, H);
    norm_rope<<<(NT*(NH+NKV))/4, 256, 0, stream>>>(QKV, cosb, sinb, qw, kw);
    vtrans<<<2048, 256, 0, stream>>>(QKV, Vt);
    attn_fwd<<<dim3(SS/128, NH, BB), 256, 0, stream>>>(QKV, Vt, attnb);
    gemm_bt<1><<<dim3(H/128, NT/128), 256, 0, stream>>>(attnb, WoT, bo, out, NT, H, NQK);
}

// Round 3
// 484.368 us; speedup vs baseline: 2.2083x; 1.2549x over previous
//
#include <hip/hip_runtime.h>
#include <math.h>

#define H 2048
#define NH 16
#define NKV 4
#define HD 128
#define BB 2
#define SS 2048
#define NT (BB*SS)           // 4096 tokens
#define NQK (NH*HD)          // 2048
#define NKVD (NKV*HD)        // 512
#define NQKV (NQK + 2*NKVD)  // 3072
#define EPSV 1e-6f
#define SM_SCALE 0.08838834764831845f

using s8v = __attribute__((ext_vector_type(8))) short;
using s4v = __attribute__((ext_vector_type(4))) short;
using f4v = __attribute__((ext_vector_type(4))) float;

typedef unsigned int __attribute__((address_space(1))) u32_g;
typedef unsigned int __attribute__((address_space(3))) u32_l;

__device__ inline float bf2f(short s){ unsigned u = ((unsigned)(unsigned short)s) << 16; return __builtin_bit_cast(float, u); }
__device__ inline short f2bf(float f){ unsigned u = __builtin_bit_cast(unsigned, f); u += 0x7FFF + ((u>>16)&1); return (short)(u>>16); }

__device__ inline f4v mfma16(s8v a, s8v b, f4v c){
    return __builtin_amdgcn_mfma_f32_16x16x32_bf16(a, b, c, 0, 0, 0);
}

__device__ inline void gl_lds16(const short* g, short* l){
    __builtin_amdgcn_global_load_lds((const u32_g*)g, (u32_l*)l, 16, 0, 0);
}

// ---------------- conversion / prep kernels ----------------

__global__ void cvt_f32_bf16(const float* __restrict__ in, short* __restrict__ out, int n4){
    int i = blockIdx.x*blockDim.x + threadIdx.x;
    int stride = gridDim.x*blockDim.x;
    for (; i < n4; i += stride){
        float4 v = reinterpret_cast<const float4*>(in)[i];
        s4v o = { f2bf(v.x), f2bf(v.y), f2bf(v.z), f2bf(v.w) };
        reinterpret_cast<s4v*>(out)[i] = o;
    }
}

// fp32 src [R][C] -> bf16 dst [C][R]; R, C multiples of 64
__global__ __launch_bounds__(256) void transpose_cvt(const float* __restrict__ src, short* __restrict__ dst,
                                                     int R, int C){
    __shared__ short t[64][72];
    const int tid = threadIdx.x;
    const int r0 = blockIdx.y*64, c0 = blockIdx.x*64;
    #pragma unroll
    for (int it = 0; it < 4; ++it){
        int ch = tid + it*256;
        int row = ch >> 4, c4 = (ch & 15) * 4;
        float4 v = *reinterpret_cast<const float4*>(src + (size_t)(r0+row)*C + c0 + c4);
        t[row][c4+0] = f2bf(v.x); t[row][c4+1] = f2bf(v.y);
        t[row][c4+2] = f2bf(v.z); t[row][c4+3] = f2bf(v.w);
    }
    __syncthreads();
    #pragma unroll
    for (int it = 0; it < 4; ++it){
        int ch = tid + it*256;
        int cc = ch >> 4, r4 = (ch & 15) * 4;
        s4v o = { t[r4+0][cc], t[r4+1][cc], t[r4+2][cc], t[r4+3][cc] };
        *reinterpret_cast<s4v*>(dst + (size_t)(c0+cc)*R + r0 + r4) = o;
    }
}

__global__ void concat_b(const float* __restrict__ bq, const float* __restrict__ bk,
                         const float* __restrict__ bv, float* __restrict__ Bc){
    int i = blockIdx.x*blockDim.x + threadIdx.x;
    if (i < NQKV)
        Bc[i] = (i < NQK) ? bq[i] : (i < NQK+NKVD ? bk[i-NQK] : bv[i-NQK-NKVD]);
}

// ---------------- m97-style GEMM: C = A @ BT^T + bias ----------------

template<int OUT_F32>
__global__ __launch_bounds__(256) void gemm_bt(const short* __restrict__ A, const short* __restrict__ BT,
                                               const float* __restrict__ bias, void* __restrict__ Cout,
                                               int M, int N, int K){
    __shared__ short As[2][4096];
    __shared__ short Bs[2][4096];
    const int tid  = threadIdx.x;
    const int lane = tid & 63;
    const int wv   = tid >> 6;
    const int f    = lane & 15;
    const int g    = lane >> 4;
    const int m0   = blockIdx.y * 128;
    const int n0   = blockIdx.x * 128;
    const int mb   = (wv & 1) * 64;
    const int nb   = (wv >> 1) * 64;
    f4v acc[4][4] = {};

    const short* Abase = A  + (size_t)m0*K;
    const short* Bbase = BT + (size_t)n0*K;
    const int srow = (lane >> 2);
    const int scol = (lane & 3) * 8;

    auto STAGE = [&](int buf, int k0){
        #pragma unroll
        for (int c = 0; c < 2; ++c){
            int issue = wv + c*4;
            int row = issue*16 + srow;
            gl_lds16(Abase + (size_t)row*K + k0 + scol, &As[buf][issue*512]);
            gl_lds16(Bbase + (size_t)row*K + k0 + scol, &Bs[buf][issue*512]);
        }
    };

    STAGE(0, 0);
    asm volatile("s_waitcnt vmcnt(0)" ::: "memory");
    __syncthreads();
    int cur = 0;
    for (int k0 = 0; k0 < K; k0 += 32){
        if (k0 + 32 < K) STAGE(cur^1, k0 + 32);
        s8v a[4], bfr[4];
        #pragma unroll
        for (int i = 0; i < 4; ++i) a[i]   = *reinterpret_cast<const s8v*>(&As[cur][(mb + i*16 + f)*32 + g*8]);
        #pragma unroll
        for (int j = 0; j < 4; ++j) bfr[j] = *reinterpret_cast<const s8v*>(&Bs[cur][(nb + j*16 + f)*32 + g*8]);
        #pragma unroll
        for (int i = 0; i < 4; ++i)
            #pragma unroll
            for (int j = 0; j < 4; ++j)
                acc[i][j] = mfma16(a[i], bfr[j], acc[i][j]);
        asm volatile("s_waitcnt vmcnt(0)" ::: "memory");
        __syncthreads();
        cur ^= 1;
    }

    #pragma unroll
    for (int i = 0; i < 4; ++i){
        #pragma unroll
        for (int j = 0; j < 4; ++j){
            int col = n0 + nb + j*16 + f;
            float bvv = bias ? bias[col] : 0.f;
            #pragma unroll
            for (int r = 0; r < 4; ++r){
                int row = m0 + mb + i*16 + g*4 + r;
                float vv = acc[i][j][r] + bvv;
                if (OUT_F32) reinterpret_cast<float*>(Cout)[(size_t)row*N + col] = vv;
                else         reinterpret_cast<short*>(Cout)[(size_t)row*N + col] = f2bf(vv);
            }
        }
    }
}

// ---------------- fused RMSNorm + RoPE on q,k (in place, bf16) ----------------

__global__ __launch_bounds__(256) void norm_rope(short* __restrict__ qkv, const float* __restrict__ cosb,
                                                 const float* __restrict__ sinb, const float* __restrict__ qw,
                                                 const float* __restrict__ kw){
    int row  = blockIdx.x * 4 + (threadIdx.x >> 6);
    int lane = threadIdx.x & 63;
    const int QROWS = NT * NH;
    short* ptr; const float* w; float outscale; int token;
    if (row < QROWS){
        token = row >> 4; int h = row & 15;
        ptr = qkv + (size_t)token*NQKV + h*HD; w = qw; outscale = SM_SCALE;
    } else {
        int rr = row - QROWS;
        token = rr >> 2; int h = rr & 3;
        ptr = qkv + (size_t)token*NQKV + NQK + h*HD; w = kw; outscale = 1.f;
    }
    int s = token & (SS-1);
    float x1 = bf2f(ptr[lane]), x2 = bf2f(ptr[lane+64]);
    float ssq = x1*x1 + x2*x2;
    #pragma unroll
    for (int off = 32; off; off >>= 1) ssq += __shfl_xor(ssq, off, 64);
    float inv = rsqrtf(ssq * (1.f/128.f) + EPSV);
    float n1 = x1 * inv * w[lane];
    float n2 = x2 * inv * w[lane+64];
    float c1 = cosb[s*HD + lane], c2 = cosb[s*HD + lane + 64];
    float s1 = sinb[s*HD + lane], s2 = sinb[s*HD + lane + 64];
    float o1 = (n1*c1 - n2*s1) * outscale;
    float o2 = (n2*c2 + n1*s2) * outscale;
    ptr[lane]    = f2bf(o1);
    ptr[lane+64] = f2bf(o2);
}

// ---------------- tiled V transpose: qkv v-part -> Vt[b*NKVD + c][s] ----------------
// grid (SS/64, NKVD/64, BB)

__global__ __launch_bounds__(256) void vtrans(const short* __restrict__ qkv, short* __restrict__ Vt){
    __shared__ short t[64][72];
    const int tid = threadIdx.x;
    const int s0 = blockIdx.x*64, c0 = blockIdx.y*64, b = blockIdx.z;
    #pragma unroll
    for (int it = 0; it < 2; ++it){
        int ch = tid + it*256;
        int row = ch >> 3, col = (ch & 7)*8;
        s8v v = *reinterpret_cast<const s8v*>(qkv + (size_t)(b*SS + s0 + row)*NQKV + NQK + NKVD + c0 + col);
        *reinterpret_cast<s8v*>(&t[row][col]) = v;
    }
    __syncthreads();
    #pragma unroll
    for (int it = 0; it < 2; ++it){
        int ch = tid + it*256;
        int cc = ch >> 3, sc = (ch & 7)*8;
        s8v o;
        #pragma unroll
        for (int j = 0; j < 8; ++j) o[j] = t[sc + j][cc];
        *reinterpret_cast<s8v*>(Vt + (size_t)(b*NKVD + c0 + cc)*SS + s0 + sc) = o;
    }
}

// ---------------- flash attention (causal, GQA 4:1) ----------------
// grid (16, NH, B); 4 waves; block owns 128 q rows, wave owns 32 (row-interleaved).
// K dbuf + V single-buf staged in swizzled LDS via global_load_lds; counted vmcnt.

__global__ __launch_bounds__(256) void attn_fwd(const short* __restrict__ qkv, const short* __restrict__ Vt,
                                                short* __restrict__ attn){
    __shared__ short Ks[2][8192];   // 64 keys x 128 d, XOR-swizzled        (32 KB)
    __shared__ short Vs[8192];      // 128 d x 64 s, XOR-swizzled           (16 KB)
    __shared__ short Ps[4][2048];   // per-wave P: 32 q x 64 k, swizzled    (16 KB)
    const int tid  = threadIdx.x;
    const int lane = tid & 63;
    const int w    = tid >> 6;
    const int f    = lane & 15;
    const int g    = lane >> 4;
    const int qt   = (int)gridDim.x - 1 - (int)blockIdx.x;  // heavy tiles first
    const int h    = blockIdx.y;
    const int b    = blockIdx.z;
    const int kvh  = h >> 2;
    const int q0   = qt * 128;
    char* Pb = (char*)Ps[w];

    auto STAGEK = [&](int buf, int kv0){
        #pragma unroll
        for (int c = 0; c < 4; ++c){
            int issue = w + c*4;
            int row = issue*4 + g;
            int col16 = f ^ (row & 7);
            gl_lds16(qkv + (size_t)(b*SS + kv0 + row)*NQKV + NQK + kvh*HD + col16*8,
                     &Ks[buf][issue*512]);
        }
    };
    // V tile: Vs[row=d 0..127][64 s], swizzled in 16B slots (col16 0..7)
    auto STAGEV = [&](int kv0){
        #pragma unroll
        for (int c = 0; c < 4; ++c){
            int issue = w + c*4;
            int row = issue*8 + (lane >> 3);
            int col16 = (lane & 7) ^ (row & 7);
            gl_lds16(Vt + (size_t)(b*NKVD + kvh*HD + row)*SS + kv0 + col16*8,
                     &Vs[issue*512]);
        }
    };

    // Q fragments
    s8v qa[2][4];
    const int qrow_a = q0 + w*4 + (f & 3) + ((f >> 2) << 4);
    #pragma unroll
    for (int i = 0; i < 2; ++i)
        #pragma unroll
        for (int dc = 0; dc < 4; ++dc)
            qa[i][dc] = *reinterpret_cast<const s8v*>(
                qkv + (size_t)(b*SS + qrow_a + i*64)*NQKV + h*HD + dc*32 + g*8);

    f4v acc[2][8] = {};
    float m_[2][4], l_[2][4];
    #pragma unroll
    for (int i = 0; i < 2; ++i)
        #pragma unroll
        for (int r = 0; r < 4; ++r){ m_[i][r] = -3e38f; l_[i][r] = 0.f; }

    const int nt = qt*2 + 2;
    STAGEK(0, 0);
    asm volatile("s_waitcnt vmcnt(0)" ::: "memory");
    __builtin_amdgcn_sched_barrier(0);
    __builtin_amdgcn_s_barrier();
    int cur = 0;

    for (int t = 0; t < nt; ++t){
        const int kv0 = t*64;
        STAGEV(kv0);                          // 4 loads (oldest)
        if (t + 1 < nt) STAGEK(cur^1, kv0 + 64);  // 4 loads (newest)

        // ---- QK^T ----
        f4v sf[2][4] = {};
        #pragma unroll
        for (int kh = 0; kh < 4; ++kh){
            s8v kb[4];
            const int krow = kh*16 + f;
            #pragma unroll
            for (int dc = 0; dc < 4; ++dc)
                kb[dc] = *reinterpret_cast<const s8v*>(
                    (const char*)Ks[cur] + krow*256 + ((dc*64 + g*16) ^ ((krow & 7) << 4)));
            #pragma unroll
            for (int i = 0; i < 2; ++i)
                #pragma unroll
                for (int dc = 0; dc < 4; ++dc)
                    sf[i][kh] = mfma16(qa[i][dc], kb[dc], sf[i][kh]);
        }

        // ---- causal mask ----
        if (kv0 + 63 > q0 + w*4){
            #pragma unroll
            for (int i = 0; i < 2; ++i)
                #pragma unroll
                for (int kh = 0; kh < 4; ++kh){
                    int key = kv0 + kh*16 + f;
                    #pragma unroll
                    for (int r = 0; r < 4; ++r){
                        int qrow = q0 + w*4 + r + g*16 + i*64;
                        if (key > qrow) sf[i][kh][r] = -3e38f;
                    }
                }
        }

        // ---- online softmax (defer-max, THR=8) ----
        float pm[2][4];
        bool need = false;
        #pragma unroll
        for (int i = 0; i < 2; ++i)
            #pragma unroll
            for (int r = 0; r < 4; ++r){
                float mx = fmaxf(fmaxf(sf[i][0][r], sf[i][1][r]), fmaxf(sf[i][2][r], sf[i][3][r]));
                #pragma unroll
                for (int off = 8; off; off >>= 1) mx = fmaxf(mx, __shfl_xor(mx, off, 16));
                pm[i][r] = mx;
                need = need || (mx > m_[i][r] + 8.f);
            }
        if (__any(need)){
            #pragma unroll
            for (int i = 0; i < 2; ++i)
                #pragma unroll
                for (int r = 0; r < 4; ++r){
                    float mn = fmaxf(m_[i][r], pm[i][r]);
                    float al = __expf(m_[i][r] - mn);
                    m_[i][r] = mn;
                    l_[i][r] *= al;
                    #pragma unroll
                    for (int df = 0; df < 8; ++df) acc[i][df][r] *= al;
                }
        }

        // ---- P = exp(S - m) -> swizzled per-wave LDS; accumulate l ----
        #pragma unroll
        for (int i = 0; i < 2; ++i)
            #pragma unroll
            for (int r = 0; r < 4; ++r){
                const int prow = i*16 + g*4 + r;
                float ps = 0.f;
                #pragma unroll
                for (int kh = 0; kh < 4; ++kh){
                    float p = __expf(sf[i][kh][r] - m_[i][r]);
                    short pb = f2bf(p);
                    ps += bf2f(pb);
                    *(short*)(Pb + prow*128 + ((unsigned)((kh*16 + f)*2) ^ ((prow & 7) << 4))) = pb;
                }
                #pragma unroll
                for (int off = 8; off; off >>= 1) ps += __shfl_xor(ps, off, 16);
                l_[i][r] += ps;
            }

        // ---- mid barrier: my V loads + my LDS ops drained; K prefetch stays in flight ----
        if (t + 1 < nt) { asm volatile("s_waitcnt vmcnt(4) lgkmcnt(0)" ::: "memory"); }
        else            { asm volatile("s_waitcnt vmcnt(0) lgkmcnt(0)" ::: "memory"); }
        __builtin_amdgcn_sched_barrier(0);
        __builtin_amdgcn_s_barrier();

        // ---- PV: O += P @ V from LDS ----
        #pragma unroll
        for (int ks = 0; ks < 2; ++ks){
            s8v pa[2];
            #pragma unroll
            for (int i = 0; i < 2; ++i){
                const int prow = i*16 + f;
                pa[i] = *reinterpret_cast<const s8v*>(
                    Pb + prow*128 + ((ks*64 + g*16) ^ ((prow & 7) << 4)));
            }
            s8v vb[8];
            #pragma unroll
            for (int df = 0; df < 8; ++df){
                const int vrow = df*16 + f;
                vb[df] = *reinterpret_cast<const s8v*>(
                    (const char*)Vs + vrow*128 + ((ks*64 + g*16) ^ ((vrow & 7) << 4)));
            }
            #pragma unroll
            for (int i = 0; i < 2; ++i)
                #pragma unroll
                for (int df = 0; df < 8; ++df)
                    acc[i][df] = mfma16(pa[i], vb[df], acc[i][df]);
        }

        // ---- end barrier: K prefetch landed; PV LDS reads serviced before next V overwrite ----
        asm volatile("s_waitcnt vmcnt(0) lgkmcnt(0)" ::: "memory");
        __builtin_amdgcn_sched_barrier(0);
        __builtin_amdgcn_s_barrier();
        cur ^= 1;
    }

    // ---- epilogue ----
    #pragma unroll
    for (int i = 0; i < 2; ++i)
        #pragma unroll
        for (int r = 0; r < 4; ++r){
            int qrow = q0 + w*4 + r + g*16 + i*64;
            float inv = 1.f / l_[i][r];
            short* ob = attn + (size_t)(b*SS + qrow)*NQK + h*HD;
            #pragma unroll
            for (int df = 0; df < 8; ++df)
                ob[df*16 + f] = f2bf(acc[i][df][r] * inv);
        }
}

// ---------------- launch ----------------

extern "C" void kernel_launch(void* const* d_in, const int* in_sizes, int n_in,
                              void* d_out, int out_size, void* d_ws, size_t ws_size,
                              hipStream_t stream){
    (void)in_sizes; (void)n_in; (void)out_size; (void)ws_size;
    const float* hs   = (const float*)d_in[0];
    const float* cosb = (const float*)d_in[1];
    const float* sinb = (const float*)d_in[2];
    const float* Wq   = (const float*)d_in[3];
    const float* bq   = (const float*)d_in[4];
    const float* Wk   = (const float*)d_in[5];
    const float* bk   = (const float*)d_in[6];
    const float* Wv   = (const float*)d_in[7];
    const float* bv   = (const float*)d_in[8];
    const float* Wo   = (const float*)d_in[9];
    const float* bo   = (const float*)d_in[10];
    const float* qw   = (const float*)d_in[11];
    const float* kw   = (const float*)d_in[12];
    float* out = (float*)d_out;
    char* ws = (char*)d_ws;

    size_t off = 0;
    auto alloc = [&](size_t bytes){ size_t o = off; off += (bytes + 255) & ~(size_t)255; return o; };
    short* Xb    = (short*)(ws + alloc((size_t)NT*H*2));
    short* Wct   = (short*)(ws + alloc((size_t)NQKV*H*2));
    float* Bc    = (float*)(ws + alloc((size_t)NQKV*4));
    short* QKV   = (short*)(ws + alloc((size_t)NT*NQKV*2));
    short* Vt    = (short*)(ws + alloc((size_t)BB*NKVD*SS*2 + 4096));
    short* attnb = (short*)(ws + alloc((size_t)NT*NQK*2));
    short* WoT   = (short*)(ws + alloc((size_t)H*NQK*2));

    cvt_f32_bf16<<<2048, 256, 0, stream>>>(hs, Xb, NT*H/4);
    transpose_cvt<<<dim3(NQK/64,  H/64), 256, 0, stream>>>(Wq, Wct,                        H, NQK);
    transpose_cvt<<<dim3(NKVD/64, H/64), 256, 0, stream>>>(Wk, Wct + (size_t)NQK*H,        H, NKVD);
    transpose_cvt<<<dim3(NKVD/64, H/64), 256, 0, stream>>>(Wv, Wct + (size_t)(NQK+NKVD)*H, H, NKVD);
    transpose_cvt<<<dim3(H/64,  NQK/64), 256, 0, stream>>>(Wo, WoT,                        NQK, H);
    concat_b<<<3, 1024, 0, stream>>>(bq, bk, bv, Bc);

    gemm_bt<0><<<dim3(NQKV/128, NT/128), 256, 0, stream>>>(Xb, Wct, Bc, QKV, NT, NQKV, H);
    norm_rope<<<(NT*(NH+NKV))/4, 256, 0, stream>>>(QKV, cosb, sinb, qw, kw);
    vtrans<<<dim3(SS/64, NKVD/64, BB), 256, 0, stream>>>(QKV, Vt);
    attn_fwd<<<dim3(SS/128, NH, BB), 256, 0, stream>>>(QKV, Vt, attnb);
    gemm_bt<1><<<dim3(H/128, NT/128), 256, 0, stream>>>(attnb, WoT, bo, out, NT, H, NQK);
}

// Round 5
// 411.526 us; speedup vs baseline: 2.5991x; 1.1770x over previous
//
#include <hip/hip_runtime.h>
#include <math.h>

#define H 2048
#define NH 16
#define NKV 4
#define HD 128
#define BB 2
#define SS 2048
#define NT (BB*SS)           // 4096 tokens
#define NQK (NH*HD)          // 2048
#define NKVD (NKV*HD)        // 512
#define NQKV (NQK + 2*NKVD)  // 3072
#define EPSV 1e-6f
#define SM_SCALE 0.08838834764831845f

using s8v = __attribute__((ext_vector_type(8))) short;
using s4v = __attribute__((ext_vector_type(4))) short;
using f4v = __attribute__((ext_vector_type(4))) float;

typedef unsigned int __attribute__((address_space(1))) u32_g;
typedef unsigned int __attribute__((address_space(3))) u32_l;

__device__ inline float bf2f(short s){ unsigned u = ((unsigned)(unsigned short)s) << 16; return __builtin_bit_cast(float, u); }
__device__ inline short f2bf(float f){ unsigned u = __builtin_bit_cast(unsigned, f); u += 0x7FFF + ((u>>16)&1); return (short)(u>>16); }

__device__ inline f4v mfma16(s8v a, s8v b, f4v c){
    return __builtin_amdgcn_mfma_f32_16x16x32_bf16(a, b, c, 0, 0, 0);
}

__device__ inline void gl_lds16(const short* g, short* l){
    __builtin_amdgcn_global_load_lds((const u32_g*)g, (u32_l*)l, 16, 0, 0);
}

// ---------------- conversion / prep kernels ----------------

__global__ void cvt_f32_bf16(const float* __restrict__ in, short* __restrict__ out, int n4){
    int i = blockIdx.x*blockDim.x + threadIdx.x;
    int stride = gridDim.x*blockDim.x;
    for (; i < n4; i += stride){
        float4 v = reinterpret_cast<const float4*>(in)[i];
        s4v o = { f2bf(v.x), f2bf(v.y), f2bf(v.z), f2bf(v.w) };
        reinterpret_cast<s4v*>(out)[i] = o;
    }
}

// fp32 src [R][C] -> bf16 dst [C][R]; R, C multiples of 64
__global__ __launch_bounds__(256) void transpose_cvt(const float* __restrict__ src, short* __restrict__ dst,
                                                     int R, int C){
    __shared__ short t[64][72];
    const int tid = threadIdx.x;
    const int r0 = blockIdx.y*64, c0 = blockIdx.x*64;
    #pragma unroll
    for (int it = 0; it < 4; ++it){
        int ch = tid + it*256;
        int row = ch >> 4, c4 = (ch & 15) * 4;
        float4 v = *reinterpret_cast<const float4*>(src + (size_t)(r0+row)*C + c0 + c4);
        t[row][c4+0] = f2bf(v.x); t[row][c4+1] = f2bf(v.y);
        t[row][c4+2] = f2bf(v.z); t[row][c4+3] = f2bf(v.w);
    }
    __syncthreads();
    #pragma unroll
    for (int it = 0; it < 4; ++it){
        int ch = tid + it*256;
        int cc = ch >> 4, r4 = (ch & 15) * 4;
        s4v o = { t[r4+0][cc], t[r4+1][cc], t[r4+2][cc], t[r4+3][cc] };
        *reinterpret_cast<s4v*>(dst + (size_t)(c0+cc)*R + r0 + r4) = o;
    }
}

__global__ void concat_b(const float* __restrict__ bq, const float* __restrict__ bk,
                         const float* __restrict__ bv, float* __restrict__ Bc){
    int i = blockIdx.x*blockDim.x + threadIdx.x;
    if (i < NQKV)
        Bc[i] = (i < NQK) ? bq[i] : (i < NQK+NKVD ? bk[i-NQK] : bv[i-NQK-NKVD]);
}

// ---------------- m97-style GEMM: C = A @ BT^T + bias ----------------

template<int OUT_F32>
__global__ __launch_bounds__(256) void gemm_bt(const short* __restrict__ A, const short* __restrict__ BT,
                                               const float* __restrict__ bias, void* __restrict__ Cout,
                                               int M, int N, int K){
    __shared__ short As[2][4096];
    __shared__ short Bs[2][4096];
    const int tid  = threadIdx.x;
    const int lane = tid & 63;
    const int wv   = tid >> 6;
    const int f    = lane & 15;
    const int g    = lane >> 4;
    const int m0   = blockIdx.y * 128;
    const int n0   = blockIdx.x * 128;
    const int mb   = (wv & 1) * 64;
    const int nb   = (wv >> 1) * 64;
    f4v acc[4][4] = {};

    const short* Abase = A  + (size_t)m0*K;
    const short* Bbase = BT + (size_t)n0*K;
    const int srow = (lane >> 2);
    const int scol = (lane & 3) * 8;

    auto STAGE = [&](int buf, int k0){
        #pragma unroll
        for (int c = 0; c < 2; ++c){
            int issue = wv + c*4;
            int row = issue*16 + srow;
            gl_lds16(Abase + (size_t)row*K + k0 + scol, &As[buf][issue*512]);
            gl_lds16(Bbase + (size_t)row*K + k0 + scol, &Bs[buf][issue*512]);
        }
    };

    STAGE(0, 0);
    asm volatile("s_waitcnt vmcnt(0)" ::: "memory");
    __syncthreads();
    int cur = 0;
    for (int k0 = 0; k0 < K; k0 += 32){
        if (k0 + 32 < K) STAGE(cur^1, k0 + 32);
        s8v a[4], bfr[4];
        #pragma unroll
        for (int i = 0; i < 4; ++i) a[i]   = *reinterpret_cast<const s8v*>(&As[cur][(mb + i*16 + f)*32 + g*8]);
        #pragma unroll
        for (int j = 0; j < 4; ++j) bfr[j] = *reinterpret_cast<const s8v*>(&Bs[cur][(nb + j*16 + f)*32 + g*8]);
        #pragma unroll
        for (int i = 0; i < 4; ++i)
            #pragma unroll
            for (int j = 0; j < 4; ++j)
                acc[i][j] = mfma16(a[i], bfr[j], acc[i][j]);
        asm volatile("s_waitcnt vmcnt(0)" ::: "memory");
        __syncthreads();
        cur ^= 1;
    }

    #pragma unroll
    for (int i = 0; i < 4; ++i){
        #pragma unroll
        for (int j = 0; j < 4; ++j){
            int col = n0 + nb + j*16 + f;
            float bvv = bias ? bias[col] : 0.f;
            #pragma unroll
            for (int r = 0; r < 4; ++r){
                int row = m0 + mb + i*16 + g*4 + r;
                float vv = acc[i][j][r] + bvv;
                if (OUT_F32) reinterpret_cast<float*>(Cout)[(size_t)row*N + col] = vv;
                else         reinterpret_cast<short*>(Cout)[(size_t)row*N + col] = f2bf(vv);
            }
        }
    }
}

// ---------------- fused RMSNorm + RoPE on q,k (in place, bf16) ----------------

__global__ __launch_bounds__(256) void norm_rope(short* __restrict__ qkv, const float* __restrict__ cosb,
                                                 const float* __restrict__ sinb, const float* __restrict__ qw,
                                                 const float* __restrict__ kw){
    int row  = blockIdx.x * 4 + (threadIdx.x >> 6);
    int lane = threadIdx.x & 63;
    const int QROWS = NT * NH;
    short* ptr; const float* w; float outscale; int token;
    if (row < QROWS){
        token = row >> 4; int h = row & 15;
        ptr = qkv + (size_t)token*NQKV + h*HD; w = qw; outscale = SM_SCALE;
    } else {
        int rr = row - QROWS;
        token = rr >> 2; int h = rr & 3;
        ptr = qkv + (size_t)token*NQKV + NQK + h*HD; w = kw; outscale = 1.f;
    }
    int s = token & (SS-1);
    float x1 = bf2f(ptr[lane]), x2 = bf2f(ptr[lane+64]);
    float ssq = x1*x1 + x2*x2;
    #pragma unroll
    for (int off = 32; off; off >>= 1) ssq += __shfl_xor(ssq, off, 64);
    float inv = rsqrtf(ssq * (1.f/128.f) + EPSV);
    float n1 = x1 * inv * w[lane];
    float n2 = x2 * inv * w[lane+64];
    float c1 = cosb[s*HD + lane], c2 = cosb[s*HD + lane + 64];
    float s1 = sinb[s*HD + lane], s2 = sinb[s*HD + lane + 64];
    float o1 = (n1*c1 - n2*s1) * outscale;
    float o2 = (n2*c2 + n1*s2) * outscale;
    ptr[lane]    = f2bf(o1);
    ptr[lane+64] = f2bf(o2);
}

// ---------------- tiled V transpose: qkv v-part -> Vt[b*NKVD + c][s] ----------------
// grid (SS/64, NKVD/64, BB)

__global__ __launch_bounds__(256) void vtrans(const short* __restrict__ qkv, short* __restrict__ Vt){
    __shared__ short t[64][72];
    const int tid = threadIdx.x;
    const int s0 = blockIdx.x*64, c0 = blockIdx.y*64, b = blockIdx.z;
    #pragma unroll
    for (int it = 0; it < 2; ++it){
        int ch = tid + it*256;
        int row = ch >> 3, col = (ch & 7)*8;
        s8v v = *reinterpret_cast<const s8v*>(qkv + (size_t)(b*SS + s0 + row)*NQKV + NQK + NKVD + c0 + col);
        *reinterpret_cast<s8v*>(&t[row][col]) = v;
    }
    __syncthreads();
    #pragma unroll
    for (int it = 0; it < 2; ++it){
        int ch = tid + it*256;
        int cc = ch >> 3, sc = (ch & 7)*8;
        s8v o;
        #pragma unroll
        for (int j = 0; j < 8; ++j) o[j] = t[sc + j][cc];
        *reinterpret_cast<s8v*>(Vt + (size_t)(b*NKVD + c0 + cc)*SS + s0 + sc) = o;
    }
}

// ---------------- flash attention (causal, GQA 4:1) ----------------
// grid (64, NKV, BB); 512 threads = 8 waves. Block = 4 q-heads of one KV head,
// 32 q-rows each (wave w -> head w>>1, row-half w&1). K,V double-buffered in
// swizzled LDS via global_load_lds; ONE barrier per KV tile.

__global__ __launch_bounds__(512, 4) void attn_fwd(const short* __restrict__ qkv, const short* __restrict__ Vt,
                                                   short* __restrict__ attn){
    __shared__ short Ks[2][8192];   // 64 keys x 128 d, XOR-swizzled  (32 KB)
    __shared__ short Vs[2][8192];   // 128 d x 64 s,  XOR-swizzled    (32 KB)
    __shared__ short Ps[8][1024];   // per-wave P: 16 q x 64 k        (16 KB)
    const int tid  = threadIdx.x;
    const int lane = tid & 63;
    const int w    = tid >> 6;
    const int f    = lane & 15;
    const int g    = lane >> 4;
    const int qt   = 63 - (int)blockIdx.x;      // heavy tiles first
    const int kvh  = blockIdx.y;
    const int b    = blockIdx.z;
    const int h    = kvh*4 + (w >> 1);
    const int half = w & 1;
    const int q0   = qt * 32;                   // per-head q base
    const int qrow0 = q0 + half*16;             // this wave's 16 rows
    char* Pb = (char*)Ps[w];

    auto STAGEK = [&](int buf, int kv0){
        #pragma unroll
        for (int c = 0; c < 2; ++c){
            int issue = w + c*8;                // 0..15
            int row = issue*4 + g;              // key 0..63
            int col16 = f ^ (row & 7);
            gl_lds16(qkv + (size_t)(b*SS + kv0 + row)*NQKV + NQK + kvh*HD + col16*8,
                     &Ks[buf][issue*512]);
        }
    };
    auto STAGEV = [&](int buf, int kv0){
        #pragma unroll
        for (int c = 0; c < 2; ++c){
            int issue = w + c*8;
            int row = issue*8 + (lane >> 3);    // d 0..127
            int col16 = (lane & 7) ^ (row & 7);
            gl_lds16(Vt + (size_t)(b*NKVD + kvh*HD + row)*SS + kv0 + col16*8,
                     &Vs[buf][issue*512]);
        }
    };

    // Q fragments (A rows = f -> qrow0 + f)
    s8v qa[4];
    #pragma unroll
    for (int dc = 0; dc < 4; ++dc)
        qa[dc] = *reinterpret_cast<const s8v*>(
            qkv + (size_t)(b*SS + qrow0 + f)*NQKV + h*HD + dc*32 + g*8);

    f4v acc[8] = {};
    float m_[4], l_[4];
    #pragma unroll
    for (int r = 0; r < 4; ++r){ m_[r] = -3e38f; l_[r] = 0.f; }

    const int nt = (q0 + 32 + 63) >> 6;
    STAGEK(0, 0);
    STAGEV(0, 0);
    asm volatile("s_waitcnt vmcnt(0)" ::: "memory");
    __builtin_amdgcn_sched_barrier(0);
    __builtin_amdgcn_s_barrier();
    int cur = 0;

    for (int t = 0; t < nt; ++t){
        const int kv0 = t*64;
        if (t + 1 < nt){ STAGEK(cur^1, kv0 + 64); STAGEV(cur^1, kv0 + 64); }

        // ---- QK^T: sf[kh]; C: col=f=key, row=g*4+r=q-fragrow ----
        f4v sf[4] = {};
        #pragma unroll
        for (int kh = 0; kh < 4; ++kh){
            const int krow = kh*16 + f;
            #pragma unroll
            for (int dc = 0; dc < 4; ++dc){
                s8v kb = *reinterpret_cast<const s8v*>(
                    (const char*)Ks[cur] + krow*256 + ((dc*64 + g*16) ^ ((krow & 7) << 4)));
                sf[kh] = mfma16(qa[dc], kb, sf[kh]);
            }
        }

        // ---- causal mask ----
        if (kv0 + 63 > qrow0){
            #pragma unroll
            for (int kh = 0; kh < 4; ++kh){
                int key = kv0 + kh*16 + f;
                #pragma unroll
                for (int r = 0; r < 4; ++r){
                    int qrow = qrow0 + g*4 + r;
                    if (key > qrow) sf[kh][r] = -3e38f;
                }
            }
        }

        // ---- online softmax (defer-max, THR=8) ----
        float pm[4];
        bool need = false;
        #pragma unroll
        for (int r = 0; r < 4; ++r){
            float mx = fmaxf(fmaxf(sf[0][r], sf[1][r]), fmaxf(sf[2][r], sf[3][r]));
            #pragma unroll
            for (int off = 8; off; off >>= 1) mx = fmaxf(mx, __shfl_xor(mx, off, 16));
            pm[r] = mx;
            need = need || (mx > m_[r] + 8.f);
        }
        if (__any(need)){
            #pragma unroll
            for (int r = 0; r < 4; ++r){
                float mn = fmaxf(m_[r], pm[r]);
                float al = __expf(m_[r] - mn);
                m_[r] = mn;
                l_[r] *= al;
                #pragma unroll
                for (int df = 0; df < 8; ++df) acc[df][r] *= al;
            }
        }

        // ---- P = exp(S - m) -> swizzled per-wave LDS; accumulate l ----
        #pragma unroll
        for (int r = 0; r < 4; ++r){
            const int prow = g*4 + r;
            float ps = 0.f;
            #pragma unroll
            for (int kh = 0; kh < 4; ++kh){
                float p = __expf(sf[kh][r] - m_[r]);
                short pb = f2bf(p);
                ps += bf2f(pb);
                *(short*)(Pb + prow*128 + ((unsigned)((kh*16 + f)*2) ^ ((prow & 7) << 4))) = pb;
            }
            #pragma unroll
            for (int off = 8; off; off >>= 1) ps += __shfl_xor(ps, off, 16);
            l_[r] += ps;
        }

        // ---- PV: O += P @ V from LDS (P rows = f, V cols = d) ----
        #pragma unroll
        for (int ks = 0; ks < 2; ++ks){
            s8v pa = *reinterpret_cast<const s8v*>(
                Pb + f*128 + ((ks*64 + g*16) ^ ((f & 7) << 4)));
            #pragma unroll
            for (int df = 0; df < 8; ++df){
                const int vrow = df*16 + f;
                s8v vb = *reinterpret_cast<const s8v*>(
                    (const char*)Vs[cur] + vrow*128 + ((ks*64 + g*16) ^ ((vrow & 7) << 4)));
                acc[df] = mfma16(pa, vb, acc[df]);
            }
        }

        // ---- single barrier per tile: next-tile stages landed; all reads of
        //      this tile's buffers were register-consumed above ----
        asm volatile("s_waitcnt vmcnt(0)" ::: "memory");
        __builtin_amdgcn_sched_barrier(0);
        __builtin_amdgcn_s_barrier();
        cur ^= 1;
    }

    // ---- epilogue ----
    #pragma unroll
    for (int r = 0; r < 4; ++r){
        int qrow = qrow0 + g*4 + r;
        float inv = 1.f / l_[r];
        short* ob = attn + (size_t)(b*SS + qrow)*NQK + h*HD;
        #pragma unroll
        for (int df = 0; df < 8; ++df)
            ob[df*16 + f] = f2bf(acc[df][r] * inv);
    }
}

// ---------------- launch ----------------

extern "C" void kernel_launch(void* const* d_in, const int* in_sizes, int n_in,
                              void* d_out, int out_size, void* d_ws, size_t ws_size,
                              hipStream_t stream){
    (void)in_sizes; (void)n_in; (void)out_size; (void)ws_size;
    const float* hs   = (const float*)d_in[0];
    const float* cosb = (const float*)d_in[1];
    const float* sinb = (const float*)d_in[2];
    const float* Wq   = (const float*)d_in[3];
    const float* bq   = (const float*)d_in[4];
    const float* Wk   = (const float*)d_in[5];
    const float* bk   = (const float*)d_in[6];
    const float* Wv   = (const float*)d_in[7];
    const float* bv   = (const float*)d_in[8];
    const float* Wo   = (const float*)d_in[9];
    const float* bo   = (const float*)d_in[10];
    const float* qw   = (const float*)d_in[11];
    const float* kw   = (const float*)d_in[12];
    float* out = (float*)d_out;
    char* ws = (char*)d_ws;

    size_t off = 0;
    auto alloc = [&](size_t bytes){ size_t o = off; off += (bytes + 255) & ~(size_t)255; return o; };
    short* Xb    = (short*)(ws + alloc((size_t)NT*H*2));
    short* Wct   = (short*)(ws + alloc((size_t)NQKV*H*2));
    float* Bc    = (float*)(ws + alloc((size_t)NQKV*4));
    short* QKV   = (short*)(ws + alloc((size_t)NT*NQKV*2));
    short* Vt    = (short*)(ws + alloc((size_t)BB*NKVD*SS*2 + 4096));
    short* attnb = (short*)(ws + alloc((size_t)NT*NQK*2));
    short* WoT   = (short*)(ws + alloc((size_t)H*NQK*2));

    cvt_f32_bf16<<<2048, 256, 0, stream>>>(hs, Xb, NT*H/4);
    transpose_cvt<<<dim3(NQK/64,  H/64), 256, 0, stream>>>(Wq, Wct,                        H, NQK);
    transpose_cvt<<<dim3(NKVD/64, H/64), 256, 0, stream>>>(Wk, Wct + (size_t)NQK*H,        H, NKVD);
    transpose_cvt<<<dim3(NKVD/64, H/64), 256, 0, stream>>>(Wv, Wct + (size_t)(NQK+NKVD)*H, H, NKVD);
    transpose_cvt<<<dim3(H/64,  NQK/64), 256, 0, stream>>>(Wo, WoT,                        NQK, H);
    concat_b<<<3, 1024, 0, stream>>>(bq, bk, bv, Bc);

    gemm_bt<0><<<dim3(NQKV/128, NT/128), 256, 0, stream>>>(Xb, Wct, Bc, QKV, NT, NQKV, H);
    norm_rope<<<(NT*(NH+NKV))/4, 256, 0, stream>>>(QKV, cosb, sinb, qw, kw);
    vtrans<<<dim3(SS/64, NKVD/64, BB), 256, 0, stream>>>(QKV, Vt);
    attn_fwd<<<dim3(64, NKV, BB), 512, 0, stream>>>(QKV, Vt, attnb);
    gemm_bt<1><<<dim3(H/128, NT/128), 256, 0, stream>>>(attnb, WoT, bo, out, NT, H, NQK);
}

// Round 6
// 349.805 us; speedup vs baseline: 3.0577x; 1.1764x over previous
//
#include <hip/hip_runtime.h>
#include <math.h>

#define H 2048
#define NH 16
#define NKV 4
#define HD 128
#define BB 2
#define SS 2048
#define NT (BB*SS)           // 4096 tokens
#define NQK (NH*HD)          // 2048
#define NKVD (NKV*HD)        // 512
#define NQKV (NQK + 2*NKVD)  // 3072
#define EPSV 1e-6f
#define SM_SCALE 0.08838834764831845f
#define LOG2E 1.4426950408889634f

using s8v = __attribute__((ext_vector_type(8))) short;
using s4v = __attribute__((ext_vector_type(4))) short;
using f4v = __attribute__((ext_vector_type(4))) float;

typedef unsigned int __attribute__((address_space(1))) u32_g;
typedef unsigned int __attribute__((address_space(3))) u32_l;

__device__ inline float bf2f(short s){ unsigned u = ((unsigned)(unsigned short)s) << 16; return __builtin_bit_cast(float, u); }
__device__ inline short f2bf(float f){ unsigned u = __builtin_bit_cast(unsigned, f); u += 0x7FFF + ((u>>16)&1); return (short)(u>>16); }

__device__ inline f4v mfma16(s8v a, s8v b, f4v c){
    return __builtin_amdgcn_mfma_f32_16x16x32_bf16(a, b, c, 0, 0, 0);
}

__device__ inline void gl_lds16(const short* g, short* l){
    __builtin_amdgcn_global_load_lds((const u32_g*)g, (u32_l*)l, 16, 0, 0);
}

// ---------------- conversion / prep kernels ----------------

__global__ void cvt_f32_bf16(const float* __restrict__ in, short* __restrict__ out, int n4){
    int i = blockIdx.x*blockDim.x + threadIdx.x;
    int stride = gridDim.x*blockDim.x;
    for (; i < n4; i += stride){
        float4 v = reinterpret_cast<const float4*>(in)[i];
        s4v o = { f2bf(v.x), f2bf(v.y), f2bf(v.z), f2bf(v.w) };
        reinterpret_cast<s4v*>(out)[i] = o;
    }
}

// fp32 src [R][C] -> bf16 dst [C][R]; R, C multiples of 64
__global__ __launch_bounds__(256) void transpose_cvt(const float* __restrict__ src, short* __restrict__ dst,
                                                     int R, int C){
    __shared__ short t[64][72];
    const int tid = threadIdx.x;
    const int r0 = blockIdx.y*64, c0 = blockIdx.x*64;
    #pragma unroll
    for (int it = 0; it < 4; ++it){
        int ch = tid + it*256;
        int row = ch >> 4, c4 = (ch & 15) * 4;
        float4 v = *reinterpret_cast<const float4*>(src + (size_t)(r0+row)*C + c0 + c4);
        t[row][c4+0] = f2bf(v.x); t[row][c4+1] = f2bf(v.y);
        t[row][c4+2] = f2bf(v.z); t[row][c4+3] = f2bf(v.w);
    }
    __syncthreads();
    #pragma unroll
    for (int it = 0; it < 4; ++it){
        int ch = tid + it*256;
        int cc = ch >> 4, r4 = (ch & 15) * 4;
        s4v o = { t[r4+0][cc], t[r4+1][cc], t[r4+2][cc], t[r4+3][cc] };
        *reinterpret_cast<s4v*>(dst + (size_t)(c0+cc)*R + r0 + r4) = o;
    }
}

__global__ void concat_b(const float* __restrict__ bq, const float* __restrict__ bk,
                         const float* __restrict__ bv, float* __restrict__ Bc){
    int i = blockIdx.x*blockDim.x + threadIdx.x;
    if (i < NQKV)
        Bc[i] = (i < NQK) ? bq[i] : (i < NQK+NKVD ? bk[i-NQK] : bv[i-NQK-NKVD]);
}

// ---------------- m97-style GEMM: C = A @ BT^T + bias, XCD-swizzled grid ----------------

template<int OUT_F32>
__global__ __launch_bounds__(256) void gemm_bt(const short* __restrict__ A, const short* __restrict__ BT,
                                               const float* __restrict__ bias, void* __restrict__ Cout,
                                               int M, int N, int K){
    __shared__ short As[2][4096];
    __shared__ short Bs[2][4096];
    const int tid  = threadIdx.x;
    const int lane = tid & 63;
    const int wv   = tid >> 6;
    const int f    = lane & 15;
    const int g    = lane >> 4;

    // XCD-aware bijective swizzle (nwg % 8 == 0 for all our grids)
    int lin = blockIdx.y * gridDim.x + blockIdx.x;
    int cpx = (gridDim.x * gridDim.y) >> 3;
    int sw  = (lin & 7) * cpx + (lin >> 3);
    const int m0 = (sw / gridDim.x) * 128;
    const int n0 = (sw % gridDim.x) * 128;

    const int mb   = (wv & 1) * 64;
    const int nb   = (wv >> 1) * 64;
    f4v acc[4][4] = {};

    const short* Abase = A  + (size_t)m0*K;
    const short* Bbase = BT + (size_t)n0*K;
    const int srow = (lane >> 2);
    const int scol = (lane & 3) * 8;

    auto STAGE = [&](int buf, int k0){
        #pragma unroll
        for (int c = 0; c < 2; ++c){
            int issue = wv + c*4;
            int row = issue*16 + srow;
            gl_lds16(Abase + (size_t)row*K + k0 + scol, &As[buf][issue*512]);
            gl_lds16(Bbase + (size_t)row*K + k0 + scol, &Bs[buf][issue*512]);
        }
    };

    STAGE(0, 0);
    asm volatile("s_waitcnt vmcnt(0)" ::: "memory");
    __syncthreads();
    int cur = 0;
    for (int k0 = 0; k0 < K; k0 += 32){
        if (k0 + 32 < K) STAGE(cur^1, k0 + 32);
        s8v a[4], bfr[4];
        #pragma unroll
        for (int i = 0; i < 4; ++i) a[i]   = *reinterpret_cast<const s8v*>(&As[cur][(mb + i*16 + f)*32 + g*8]);
        #pragma unroll
        for (int j = 0; j < 4; ++j) bfr[j] = *reinterpret_cast<const s8v*>(&Bs[cur][(nb + j*16 + f)*32 + g*8]);
        #pragma unroll
        for (int i = 0; i < 4; ++i)
            #pragma unroll
            for (int j = 0; j < 4; ++j)
                acc[i][j] = mfma16(a[i], bfr[j], acc[i][j]);
        asm volatile("s_waitcnt vmcnt(0)" ::: "memory");
        __syncthreads();
        cur ^= 1;
    }

    #pragma unroll
    for (int i = 0; i < 4; ++i){
        #pragma unroll
        for (int j = 0; j < 4; ++j){
            int col = n0 + nb + j*16 + f;
            float bvv = bias ? bias[col] : 0.f;
            #pragma unroll
            for (int r = 0; r < 4; ++r){
                int row = m0 + mb + i*16 + g*4 + r;
                float vv = acc[i][j][r] + bvv;
                if (OUT_F32) reinterpret_cast<float*>(Cout)[(size_t)row*N + col] = vv;
                else         reinterpret_cast<short*>(Cout)[(size_t)row*N + col] = f2bf(vv);
            }
        }
    }
}

// ---------------- fused RMSNorm + RoPE on q,k (in place, bf16) ----------------
// Q gets SM_SCALE * log2(e) folded in (attention works in exp2 domain).

__global__ __launch_bounds__(256) void norm_rope(short* __restrict__ qkv, const float* __restrict__ cosb,
                                                 const float* __restrict__ sinb, const float* __restrict__ qw,
                                                 const float* __restrict__ kw){
    int row  = blockIdx.x * 4 + (threadIdx.x >> 6);
    int lane = threadIdx.x & 63;
    const int QROWS = NT * NH;
    short* ptr; const float* w; float outscale; int token;
    if (row < QROWS){
        token = row >> 4; int h = row & 15;
        ptr = qkv + (size_t)token*NQKV + h*HD; w = qw; outscale = SM_SCALE * LOG2E;
    } else {
        int rr = row - QROWS;
        token = rr >> 2; int h = rr & 3;
        ptr = qkv + (size_t)token*NQKV + NQK + h*HD; w = kw; outscale = 1.f;
    }
    int s = token & (SS-1);
    float x1 = bf2f(ptr[lane]), x2 = bf2f(ptr[lane+64]);
    float ssq = x1*x1 + x2*x2;
    #pragma unroll
    for (int off = 32; off; off >>= 1) ssq += __shfl_xor(ssq, off, 64);
    float inv = rsqrtf(ssq * (1.f/128.f) + EPSV);
    float n1 = x1 * inv * w[lane];
    float n2 = x2 * inv * w[lane+64];
    float c1 = cosb[s*HD + lane], c2 = cosb[s*HD + lane + 64];
    float s1 = sinb[s*HD + lane], s2 = sinb[s*HD + lane + 64];
    float o1 = (n1*c1 - n2*s1) * outscale;
    float o2 = (n2*c2 + n1*s2) * outscale;
    ptr[lane]    = f2bf(o1);
    ptr[lane+64] = f2bf(o2);
}

// ---------------- tiled V transpose: qkv v-part -> Vt[b*NKVD + c][s] ----------------
// grid (SS/64, NKVD/64, BB)

__global__ __launch_bounds__(256) void vtrans(const short* __restrict__ qkv, short* __restrict__ Vt){
    __shared__ short t[64][72];
    const int tid = threadIdx.x;
    const int s0 = blockIdx.x*64, c0 = blockIdx.y*64, b = blockIdx.z;
    #pragma unroll
    for (int it = 0; it < 2; ++it){
        int ch = tid + it*256;
        int row = ch >> 3, col = (ch & 7)*8;
        s8v v = *reinterpret_cast<const s8v*>(qkv + (size_t)(b*SS + s0 + row)*NQKV + NQK + NKVD + c0 + col);
        *reinterpret_cast<s8v*>(&t[row][col]) = v;
    }
    __syncthreads();
    #pragma unroll
    for (int it = 0; it < 2; ++it){
        int ch = tid + it*256;
        int cc = ch >> 3, sc = (ch & 7)*8;
        s8v o;
        #pragma unroll
        for (int j = 0; j < 8; ++j) o[j] = t[sc + j][cc];
        *reinterpret_cast<s8v*>(Vt + (size_t)(b*NKVD + c0 + cc)*SS + s0 + sc) = o;
    }
}

// ---------------- flash attention (causal, GQA 4:1) ----------------
// grid (512); 512 threads = 8 waves. bx&7 -> (kvh,b): each XCD owns ONE KV
// stream (1 MB, L2-resident). bx>>3 -> qt heavy-first. Wave w -> head w>>1,
// row-half w&1 (16 q rows). K,V dbuf in swizzled LDS; one barrier per tile.
// Softmax: exp2 domain, defer-max (no shuffles steady-state), per-lane l.

__global__ __launch_bounds__(512, 4) void attn_fwd(const short* __restrict__ qkv, const short* __restrict__ Vt,
                                                   short* __restrict__ attn){
    __shared__ short Ks[2][8192];   // 64 keys x 128 d, XOR-swizzled  (32 KB)
    __shared__ short Vs[2][8192];   // 128 d x 64 s,  XOR-swizzled    (32 KB)
    __shared__ short Ps[8][1024];   // per-wave P: 16 q x 64 k        (16 KB)
    const int tid  = threadIdx.x;
    const int lane = tid & 63;
    const int w    = tid >> 6;
    const int f    = lane & 15;
    const int g    = lane >> 4;
    const int bx   = blockIdx.x;
    const int qt   = 63 - (bx >> 3);            // heavy tiles first
    const int kvh  = bx & 3;
    const int b    = (bx >> 2) & 1;
    const int h    = kvh*4 + (w >> 1);
    const int half = w & 1;
    const int q0   = qt * 32;                   // per-head q base
    const int qrow0 = q0 + half*16;             // this wave's 16 rows
    char* Pb = (char*)Ps[w];

    auto STAGEK = [&](int buf, int kv0){
        #pragma unroll
        for (int c = 0; c < 2; ++c){
            int issue = w + c*8;                // 0..15
            int row = issue*4 + g;              // key 0..63
            int col16 = f ^ (row & 7);
            gl_lds16(qkv + (size_t)(b*SS + kv0 + row)*NQKV + NQK + kvh*HD + col16*8,
                     &Ks[buf][issue*512]);
        }
    };
    auto STAGEV = [&](int buf, int kv0){
        #pragma unroll
        for (int c = 0; c < 2; ++c){
            int issue = w + c*8;
            int row = issue*8 + (lane >> 3);    // d 0..127
            int col16 = (lane & 7) ^ (row & 7);
            gl_lds16(Vt + (size_t)(b*NKVD + kvh*HD + row)*SS + kv0 + col16*8,
                     &Vs[buf][issue*512]);
        }
    };

    // Q fragments (A rows = f -> qrow0 + f)
    s8v qa[4];
    #pragma unroll
    for (int dc = 0; dc < 4; ++dc)
        qa[dc] = *reinterpret_cast<const s8v*>(
            qkv + (size_t)(b*SS + qrow0 + f)*NQKV + h*HD + dc*32 + g*8);

    f4v acc[8] = {};
    float m_[4], lp_[4];
    #pragma unroll
    for (int r = 0; r < 4; ++r){ m_[r] = -3e38f; lp_[r] = 0.f; }

    const int nt = (q0 + 32 + 63) >> 6;
    STAGEK(0, 0);
    STAGEV(0, 0);
    asm volatile("s_waitcnt vmcnt(0)" ::: "memory");
    __builtin_amdgcn_sched_barrier(0);
    __builtin_amdgcn_s_barrier();
    int cur = 0;

    for (int t = 0; t < nt; ++t){
        const int kv0 = t*64;
        if (t + 1 < nt){ STAGEK(cur^1, kv0 + 64); STAGEV(cur^1, kv0 + 64); }

        // ---- QK^T: sf[kh]; C: col=f=key, row=g*4+r=q-fragrow ----
        f4v sf[4] = {};
        __builtin_amdgcn_s_setprio(1);
        #pragma unroll
        for (int kh = 0; kh < 4; ++kh){
            const int krow = kh*16 + f;
            #pragma unroll
            for (int dc = 0; dc < 4; ++dc){
                s8v kb = *reinterpret_cast<const s8v*>(
                    (const char*)Ks[cur] + krow*256 + ((dc*64 + g*16) ^ ((krow & 7) << 4)));
                sf[kh] = mfma16(qa[dc], kb, sf[kh]);
            }
        }
        __builtin_amdgcn_s_setprio(0);

        // ---- causal mask ----
        if (kv0 + 63 > qrow0){
            #pragma unroll
            for (int kh = 0; kh < 4; ++kh){
                int key = kv0 + kh*16 + f;
                #pragma unroll
                for (int r = 0; r < 4; ++r){
                    int qrow = qrow0 + g*4 + r;
                    if (key > qrow) sf[kh][r] = -3e38f;
                }
            }
        }

        // ---- defer-max check: per-lane only, no cross-lane reduce ----
        float mloc[4];
        bool need = false;
        #pragma unroll
        for (int r = 0; r < 4; ++r){
            mloc[r] = fmaxf(fmaxf(sf[0][r], sf[1][r]), fmaxf(sf[2][r], sf[3][r]));
            need = need || (mloc[r] > m_[r] + 11.0f);
        }
        if (__any(need)){
            #pragma unroll
            for (int r = 0; r < 4; ++r){
                float mx = mloc[r];
                #pragma unroll
                for (int off = 8; off; off >>= 1) mx = fmaxf(mx, __shfl_xor(mx, off, 16));
                float mn = fmaxf(m_[r], mx);
                float al = __builtin_amdgcn_exp2f(m_[r] - mn);
                m_[r] = mn;
                lp_[r] *= al;
                #pragma unroll
                for (int df = 0; df < 8; ++df) acc[df][r] *= al;
            }
        }

        // ---- P = exp2(S - m) -> swizzled per-wave LDS; per-lane partial l ----
        #pragma unroll
        for (int r = 0; r < 4; ++r){
            const int prow = g*4 + r;
            #pragma unroll
            for (int kh = 0; kh < 4; ++kh){
                float p = __builtin_amdgcn_exp2f(sf[kh][r] - m_[r]);
                short pb = f2bf(p);
                lp_[r] += bf2f(pb);
                *(short*)(Pb + prow*128 + ((unsigned)((kh*16 + f)*2) ^ ((prow & 7) << 4))) = pb;
            }
        }

        // ---- PV: O += P @ V from LDS (P rows = f, V cols = d) ----
        __builtin_amdgcn_s_setprio(1);
        #pragma unroll
        for (int ks = 0; ks < 2; ++ks){
            s8v pa = *reinterpret_cast<const s8v*>(
                Pb + f*128 + ((ks*64 + g*16) ^ ((f & 7) << 4)));
            #pragma unroll
            for (int df = 0; df < 8; ++df){
                const int vrow = df*16 + f;
                s8v vb = *reinterpret_cast<const s8v*>(
                    (const char*)Vs[cur] + vrow*128 + ((ks*64 + g*16) ^ ((vrow & 7) << 4)));
                acc[df] = mfma16(pa, vb, acc[df]);
            }
        }
        __builtin_amdgcn_s_setprio(0);

        // ---- single barrier per tile ----
        asm volatile("s_waitcnt vmcnt(0)" ::: "memory");
        __builtin_amdgcn_sched_barrier(0);
        __builtin_amdgcn_s_barrier();
        cur ^= 1;
    }

    // ---- epilogue: reduce per-lane l partials across the 16 f-lanes ----
    #pragma unroll
    for (int r = 0; r < 4; ++r){
        float l = lp_[r];
        #pragma unroll
        for (int off = 8; off; off >>= 1) l += __shfl_xor(l, off, 16);
        int qrow = qrow0 + g*4 + r;
        float inv = 1.f / l;
        short* ob = attn + (size_t)(b*SS + qrow)*NQK + h*HD;
        #pragma unroll
        for (int df = 0; df < 8; ++df)
            ob[df*16 + f] = f2bf(acc[df][r] * inv);
    }
}

// ---------------- launch ----------------

extern "C" void kernel_launch(void* const* d_in, const int* in_sizes, int n_in,
                              void* d_out, int out_size, void* d_ws, size_t ws_size,
                              hipStream_t stream){
    (void)in_sizes; (void)n_in; (void)out_size; (void)ws_size;
    const float* hs   = (const float*)d_in[0];
    const float* cosb = (const float*)d_in[1];
    const float* sinb = (const float*)d_in[2];
    const float* Wq   = (const float*)d_in[3];
    const float* bq   = (const float*)d_in[4];
    const float* Wk   = (const float*)d_in[5];
    const float* bk   = (const float*)d_in[6];
    const float* Wv   = (const float*)d_in[7];
    const float* bv   = (const float*)d_in[8];
    const float* Wo   = (const float*)d_in[9];
    const float* bo   = (const float*)d_in[10];
    const float* qw   = (const float*)d_in[11];
    const float* kw   = (const float*)d_in[12];
    float* out = (float*)d_out;
    char* ws = (char*)d_ws;

    size_t off = 0;
    auto alloc = [&](size_t bytes){ size_t o = off; off += (bytes + 255) & ~(size_t)255; return o; };
    short* Xb    = (short*)(ws + alloc((size_t)NT*H*2));
    short* Wct   = (short*)(ws + alloc((size_t)NQKV*H*2));
    float* Bc    = (float*)(ws + alloc((size_t)NQKV*4));
    short* QKV   = (short*)(ws + alloc((size_t)NT*NQKV*2));
    short* Vt    = (short*)(ws + alloc((size_t)BB*NKVD*SS*2 + 4096));
    short* attnb = (short*)(ws + alloc((size_t)NT*NQK*2));
    short* WoT   = (short*)(ws + alloc((size_t)H*NQK*2));

    cvt_f32_bf16<<<2048, 256, 0, stream>>>(hs, Xb, NT*H/4);
    transpose_cvt<<<dim3(NQK/64,  H/64), 256, 0, stream>>>(Wq, Wct,                        H, NQK);
    transpose_cvt<<<dim3(NKVD/64, H/64), 256, 0, stream>>>(Wk, Wct + (size_t)NQK*H,        H, NKVD);
    transpose_cvt<<<dim3(NKVD/64, H/64), 256, 0, stream>>>(Wv, Wct + (size_t)(NQK+NKVD)*H, H, NKVD);
    transpose_cvt<<<dim3(H/64,  NQK/64), 256, 0, stream>>>(Wo, WoT,                        NQK, H);
    concat_b<<<3, 1024, 0, stream>>>(bq, bk, bv, Bc);

    gemm_bt<0><<<dim3(NQKV/128, NT/128), 256, 0, stream>>>(Xb, Wct, Bc, QKV, NT, NQKV, H);
    norm_rope<<<(NT*(NH+NKV))/4, 256, 0, stream>>>(QKV, cosb, sinb, qw, kw);
    vtrans<<<dim3(SS/64, NKVD/64, BB), 256, 0, stream>>>(QKV, Vt);
    attn_fwd<<<512, 512, 0, stream>>>(QKV, Vt, attnb);
    gemm_bt<1><<<dim3(H/128, NT/128), 256, 0, stream>>>(attnb, WoT, bo, out, NT, H, NQK);
}